// Round 8
// baseline (763.364 us; speedup 1.0000x reference)
//
#include <hip/hip_runtime.h>
#include <hip/hip_bf16.h>
#include <math.h>

#define BT   16384   // B*T
#define CDIM 128
#define TSEQ 256
#define NBAT 64
#define NH   8
#define HD   16
#define NL   6
#define FFD  512
#define NV   3149

typedef __bf16 bfv8 __attribute__((ext_vector_type(8)));
typedef float  fv4  __attribute__((ext_vector_type(4)));
typedef short  s4   __attribute__((ext_vector_type(4)));
typedef unsigned short u16;
typedef unsigned int   u32;
typedef u16 u16v8 __attribute__((ext_vector_type(8)));

__device__ __forceinline__ u16 f2b(float f) {
  u32 u = __builtin_bit_cast(u32, f);
  u += 0x7FFFu + ((u >> 16) & 1u);        // round-to-nearest-even
  return (u16)(u >> 16);
}
__device__ __forceinline__ u32 cvtpk(float lo, float hi) {
  u32 r;
  asm("v_cvt_pk_bf16_f32 %0, %1, %2" : "=v"(r) : "v"(lo), "v"(hi));
  return r;
}
__device__ __forceinline__ fv4 mfma16(s4 a, s4 b, fv4 c) {
#if __has_builtin(__builtin_amdgcn_mfma_f32_16x16x16bf16_1k)
  return __builtin_amdgcn_mfma_f32_16x16x16bf16_1k(a, b, c, 0, 0, 0);
#else
  fv4 d;
  asm volatile("v_mfma_f32_16x16x16_bf16 %0, %1, %2, %3"
               : "=v"(d) : "v"(a), "v"(b), "v"(c));
  return d;
#endif
}
// async global->LDS, 16B per lane; ldst is WAVE-UNIFORM base (HW adds lane*16)
__device__ __forceinline__ void gload16(const u16* g, u16* l) {
  __builtin_amdgcn_global_load_lds(
      (const __attribute__((address_space(1))) void*)g,
      (__attribute__((address_space(3))) void*)l, 16, 0, 0);
}

// ---------------------------------------------------------------- embed ----
__global__ __launch_bounds__(256) void embed_kernel(
    const int* __restrict__ tokens, const float* __restrict__ tok_emb,
    const float* __restrict__ pos_emb, float* __restrict__ x) {
  int i4 = blockIdx.x * 256 + threadIdx.x;
  if (i4 >= BT * CDIM / 4) return;
  int i  = i4 * 4;
  int c  = i & (CDIM - 1);
  int bt = i >> 7;
  int t  = bt & (TSEQ - 1);
  int tok = tokens[bt];
  float4 te = *(const float4*)(tok_emb + (size_t)tok * CDIM + c);
  float4 pe = *(const float4*)(pos_emb + (size_t)t * CDIM + c);
  float4 r;
  r.x = te.x + pe.x; r.y = te.y + pe.y; r.z = te.z + pe.z; r.w = te.w + pe.w;
  *(float4*)(x + i) = r;
}

// ------------------------------------------------- weight pack (bf16 B^T) --
__global__ __launch_bounds__(256) void packqkv_bf16(
    const float* __restrict__ Wq, const float* __restrict__ Wk,
    const float* __restrict__ Wv, u16* __restrict__ dst) {
  int idx = blockIdx.x * 256 + threadIdx.x;
  if (idx >= NL * 384 * CDIM) return;
  int c = idx & 127;
  int j = (idx >> 7) % 384;
  int l = idx / (384 * CDIM);
  int sel = j >> 7;
  int jj  = j & 127;
  int h   = jj >> 4;
  int d   = jj & 15;
  const float* W = (sel == 0) ? Wq : (sel == 1) ? Wk : Wv;
  dst[idx] = f2b(W[(((size_t)l * NH + h) * CDIM + c) * HD + d]);
}

// tiled transpose: dst[l][c][r] = bf16(src[l][r][c]); coalesced both sides
__global__ __launch_bounds__(256) void transpose_cast_t(
    const float* __restrict__ src, u16* __restrict__ dst, int R, int C) {
  __shared__ float tile[32][33];
  int l  = blockIdx.z;
  int r0 = blockIdx.y * 32, c0 = blockIdx.x * 32;
  int tr = threadIdx.x >> 5, tc = threadIdx.x & 31;
  #pragma unroll
  for (int p = 0; p < 4; p++) {
    int r = r0 + tr + p * 8, c = c0 + tc;
    if (r < R && c < C) tile[tr + p * 8][tc] = src[((size_t)l * R + r) * C + c];
  }
  __syncthreads();
  #pragma unroll
  for (int p = 0; p < 4; p++) {
    int c = c0 + tr + p * 8, r = r0 + tc;
    if (r < R && c < C) dst[((size_t)l * C + c) * R + r] = f2b(tile[tc][tr + p * 8]);
  }
}

// -------------------------------------------- K=128 single-barrier GEMM ----
// C[M,N] = epi(A[M,128] @ Bt[N,128]^T); BM=64; entire tiles staged async in
// the prologue (global_load_lds w16, k-chunk-major LDS), ONE barrier, then a
// barrier-free 4-step MFMA loop. LN_A: A = LayerNorm(X f32) computed in-block
// (overlaps the async loads). OMODE: 0 bf16 out, 1 f32 out, 2 f32 += in-place.
template<int OMODE, bool BIAS, bool RELU, bool LN_A, int BN>
__global__ __launch_bounds__(256) void gemm_k128(
    const void* __restrict__ Ain, const u16* __restrict__ Btp,
    const float* __restrict__ lng, const float* __restrict__ lnb,
    const float* __restrict__ bias, void* __restrict__ Cout,
    int M, int N) {
  constexpr int NF = BN / 32;
  constexpr int ASZ = LN_A ? (64 * 144) : (16 * 64 * 8);
  __shared__ u16 AsF[ASZ];
  __shared__ u16 BsF[16 * BN * 8];
  const int tid  = threadIdx.x;
  const int lane = tid & 63;
  const int wv   = tid >> 6;
  const int wm   = wv & 1;
  const int wn   = wv >> 1;
  const int m0 = blockIdx.y * 64;
  const int n0 = blockIdx.x * BN;
  const int fr = lane & 15;
  const int g  = lane >> 4;

  // ---- async stage B (and A if not LN) ----
  #pragma unroll
  for (int cc = 0; cc < 4; cc++) {
    int c = wv * 4 + cc;
    #pragma unroll
    for (int p = 0; p < BN / 64; p++) {
      int n = n0 + p * 64 + lane;
      if (n < N)
        gload16(Btp + (size_t)n * 128 + c * 8, &BsF[(c * BN + p * 64) * 8]);
    }
    if (!LN_A)
      gload16((const u16*)Ain + (size_t)(m0 + lane) * 128 + c * 8,
              &AsF[(c * 64) * 8]);
  }

  // ---- LN prologue (overlaps load flight) ----
  if (LN_A) {
    const float* X = (const float*)Ain;
    const int l32  = lane & 31;
    const int rsel = lane >> 5;
    float4 gg = *(const float4*)(lng + l32 * 4);
    float4 bb = *(const float4*)(lnb + l32 * 4);
    #pragma unroll 2
    for (int it = 0; it < 8; it++) {
      int r = it * 8 + wv * 2 + rsel;
      float4 v = *(const float4*)(X + (size_t)(m0 + r) * 128 + l32 * 4);
      float s = (v.x + v.y) + (v.z + v.w);
      #pragma unroll
      for (int m = 1; m < 32; m <<= 1) s += __shfl_xor(s, m);
      float mu = s * (1.f / 128.f);
      float dx = v.x - mu, dy = v.y - mu, dz = v.z - mu, dw = v.w - mu;
      float s2 = (dx * dx + dy * dy) + (dz * dz + dw * dw);
      #pragma unroll
      for (int m = 1; m < 32; m <<= 1) s2 += __shfl_xor(s2, m);
      float rstd = rsqrtf(s2 * (1.f / 128.f) + 1e-5f);
      u32 p0 = cvtpk(dx * rstd * gg.x + bb.x, dy * rstd * gg.y + bb.y);
      u32 p1 = cvtpk(dz * rstd * gg.z + bb.z, dw * rstd * gg.w + bb.w);
      *(uint2*)&AsF[r * 144 + l32 * 4] = make_uint2(p0, p1);
    }
  }
  __syncthreads();   // drains gload_lds (vmcnt) + LN ds_writes (lgkmcnt)

  // ---- barrier-free compute: 4 K-steps of 32 ----
  fv4 acc[2][NF];
  #pragma unroll
  for (int i = 0; i < 2; i++)
    #pragma unroll
    for (int j = 0; j < NF; j++) acc[i][j] = (fv4){0.f, 0.f, 0.f, 0.f};

  #pragma unroll
  for (int ks = 0; ks < 4; ks++) {
    bfv8 a[2], b[NF];
    #pragma unroll
    for (int i = 0; i < 2; i++) {
      int row = wm * 32 + i * 16 + fr;
      if (LN_A) a[i] = *(const bfv8*)&AsF[row * 144 + ks * 32 + g * 8];
      else      a[i] = *(const bfv8*)&AsF[((4 * ks + g) * 64 + row) * 8];
    }
    #pragma unroll
    for (int j = 0; j < NF; j++)
      b[j] = *(const bfv8*)&BsF[((4 * ks + g) * BN + wn * (BN / 2) + j * 16 + fr) * 8];
    #pragma unroll
    for (int i = 0; i < 2; i++)
      #pragma unroll
      for (int j = 0; j < NF; j++)
        acc[i][j] = __builtin_amdgcn_mfma_f32_16x16x32_bf16(a[i], b[j], acc[i][j], 0, 0, 0);
  }

  // ---- epilogue ----
  const int row0 = m0 + wm * 32;
  const int col0 = n0 + wn * (BN / 2);
  const int lr   = (lane >> 4) * 4;
  #pragma unroll
  for (int j = 0; j < NF; j++) {
    int col = col0 + j * 16 + fr;
    if (col >= N) continue;
    float bz = BIAS ? bias[col] : 0.f;
    #pragma unroll
    for (int i = 0; i < 2; i++) {
      #pragma unroll
      for (int q = 0; q < 4; q++) {
        int row = row0 + i * 16 + lr + q;
        float v = acc[i][j][q] + bz;
        if (RELU) v = fmaxf(v, 0.f);
        if (OMODE == 0)      ((u16*)Cout)[(size_t)row * N + col] = f2b(v);
        else if (OMODE == 1) ((float*)Cout)[(size_t)row * N + col] = v;
        else                 ((float*)Cout)[(size_t)row * N + col] += v;
      }
    }
  }
}

// --------------------------- generic-K double-buffered GEMM (FFN2) ---------
// BM=BN=64; T3-minimum: STAGE(next) -> compute(cur) -> sync, per 32-k step.
template<int OMODE, bool BIAS, bool RELU>
__global__ __launch_bounds__(256) void gemm_dbuf64(
    const u16* __restrict__ A, const u16* __restrict__ Btp,
    const float* __restrict__ bias, void* __restrict__ Cout,
    int M, int N, int K) {
  __shared__ u16 As[2][4][64][8];
  __shared__ u16 Bs[2][4][64][8];
  const int tid  = threadIdx.x;
  const int lane = tid & 63;
  const int wv   = tid >> 6;
  const int wm   = wv & 1;
  const int wn   = wv >> 1;
  const int m0 = blockIdx.y * 64;
  const int n0 = blockIdx.x * 64;
  const int fr = lane & 15;
  const int g  = lane >> 4;

  // wave wv stages k-chunk wv (8 bf16) for all 64 rows of A and B
  const u16* agA = A   + (size_t)(m0 + lane) * K + wv * 8;
  const u16* agB = Btp + (size_t)(n0 + lane) * K + wv * 8;

  gload16(agA, &As[0][wv][0][0]);
  gload16(agB, &Bs[0][wv][0][0]);

  fv4 acc[2][2];
  #pragma unroll
  for (int i = 0; i < 2; i++)
    #pragma unroll
    for (int j = 0; j < 2; j++) acc[i][j] = (fv4){0.f, 0.f, 0.f, 0.f};

  __syncthreads();                         // buf0 resident
  int cur = 0;
  for (int k0 = 0; k0 < K; k0 += 32) {
    if (k0 + 32 < K) {                     // stage next (overlaps compute)
      gload16(agA + k0 + 32, &As[cur ^ 1][wv][0][0]);
      gload16(agB + k0 + 32, &Bs[cur ^ 1][wv][0][0]);
    }
    bfv8 a[2], b[2];
    #pragma unroll
    for (int i = 0; i < 2; i++)
      a[i] = *(const bfv8*)&As[cur][g][wm * 32 + i * 16 + fr][0];
    #pragma unroll
    for (int j = 0; j < 2; j++)
      b[j] = *(const bfv8*)&Bs[cur][g][wn * 32 + j * 16 + fr][0];
    #pragma unroll
    for (int i = 0; i < 2; i++)
      #pragma unroll
      for (int j = 0; j < 2; j++)
        acc[i][j] = __builtin_amdgcn_mfma_f32_16x16x32_bf16(a[i], b[j], acc[i][j], 0, 0, 0);
    __syncthreads();                       // next buf resident; cur free
    cur ^= 1;
  }

  const int row0 = m0 + wm * 32;
  const int col0 = n0 + wn * 32;
  const int lr   = (lane >> 4) * 4;
  #pragma unroll
  for (int j = 0; j < 2; j++) {
    int col = col0 + j * 16 + fr;
    float bz = BIAS ? bias[col] : 0.f;
    #pragma unroll
    for (int i = 0; i < 2; i++) {
      #pragma unroll
      for (int q = 0; q < 4; q++) {
        int row = row0 + i * 16 + lr + q;
        float v = acc[i][j][q] + bz;
        if (RELU) v = fmaxf(v, 0.f);
        if (OMODE == 0)      ((u16*)Cout)[(size_t)row * N + col] = f2b(v);
        else if (OMODE == 1) ((float*)Cout)[(size_t)row * N + col] = v;
        else                 ((float*)Cout)[(size_t)row * N + col] += v;
      }
    }
  }
}

// ------------------------------------------------------- MFMA attention ----
// (unchanged from R7 — isolating the GEMM delta this round)
__global__ __launch_bounds__(256) void attn_mfma(
    const u16* __restrict__ qkv, u16* __restrict__ out) {
  const float scale = 0.08838834764831843f;   // C^-0.5 (C=128, per reference!)
  __shared__ u16 Qs[128][20];
  __shared__ u16 Ks[TSEQ][20];
  __shared__ u16 Vt[HD][284];
  const int blk = blockIdx.x;
  const int qh = blk & 1;
  const int h  = (blk >> 1) & (NH - 1);
  const int b  = blk >> 4;
  const int tid = threadIdx.x;

  #pragma unroll
  for (int p = 0; p < 2; p++) {
    int idx = tid + p * 256;
    int r  = idx >> 1;
    int c8 = (idx & 1) * 8;
    const u16* base = qkv + (size_t)(b * TSEQ + r) * 384 + h * HD + c8;
    uint4 k  = *(const uint4*)(base + CDIM);
    u16v8 v  = *(const u16v8*)(base + 2 * CDIM);
    *(uint4*)&Ks[r][c8] = k;
    #pragma unroll
    for (int i = 0; i < 8; i++) Vt[c8 + i][r] = v[i];
  }
  {
    int r  = tid >> 1;
    int c8 = (tid & 1) * 8;
    const u16* base = qkv + (size_t)(b * TSEQ + qh * 128 + r) * 384 + h * HD + c8;
    *(uint4*)&Qs[r][c8] = *(const uint4*)(base);
  }
  __syncthreads();

  const int wv   = tid >> 6;
  const int lane = tid & 63;
  const int fr = lane & 15;
  const int g  = lane >> 4;

  #pragma unroll 1
  for (int qi = 0; qi < 2; qi++) {
    const int qt = qh * 8 + (qi ? (7 - wv) : wv);
    s4 qf = *(const s4*)&Qs[(qt & 7) * 16 + fr][g * 4];

    float m = -3.4e38f, l = 0.f;
    fv4 accO = (fv4){0.f, 0.f, 0.f, 0.f};

    for (int st = 0; st < qt; st++) {
      s4 kf = *(const s4*)&Ks[st * 16 + fr][g * 4];
      fv4 sc = mfma16(kf, qf, (fv4){0.f, 0.f, 0.f, 0.f});
      float s0 = sc[0] * scale, s1 = sc[1] * scale;
      float s2 = sc[2] * scale, s3 = sc[3] * scale;
      float tm = fmaxf(fmaxf(s0, s1), fmaxf(s2, s3));
      tm = fmaxf(tm, __shfl_xor(tm, 16));
      tm = fmaxf(tm, __shfl_xor(tm, 32));
      float mn = fmaxf(m, tm);
      float corr = __expf(m - mn);
      float e0 = __expf(s0 - mn), e1 = __expf(s1 - mn);
      float e2 = __expf(s2 - mn), e3 = __expf(s3 - mn);
      l = l * corr + (e0 + e1) + (e2 + e3);
      accO[0] *= corr; accO[1] *= corr; accO[2] *= corr; accO[3] *= corr;
      s4 pf = __builtin_bit_cast(s4, make_uint2(cvtpk(e0, e1), cvtpk(e2, e3)));
      s4 vf = *(const s4*)&Vt[fr][st * 16 + g * 4];
      accO = mfma16(vf, pf, accO);
      m = mn;
    }
    {
      s4 kf = *(const s4*)&Ks[qt * 16 + fr][g * 4];
      fv4 sc = mfma16(kf, qf, (fv4){0.f, 0.f, 0.f, 0.f});
      const float NEG = -3.4e38f;
      float s0 = (4 * g + 0 > fr) ? NEG : sc[0] * scale;
      float s1 = (4 * g + 1 > fr) ? NEG : sc[1] * scale;
      float s2 = (4 * g + 2 > fr) ? NEG : sc[2] * scale;
      float s3 = (4 * g + 3 > fr) ? NEG : sc[3] * scale;
      float tm = fmaxf(fmaxf(s0, s1), fmaxf(s2, s3));
      tm = fmaxf(tm, __shfl_xor(tm, 16));
      tm = fmaxf(tm, __shfl_xor(tm, 32));
      float mn = fmaxf(m, tm);
      float corr = __expf(m - mn);
      float e0 = (s0 <= -1e37f) ? 0.f : __expf(s0 - mn);
      float e1 = (s1 <= -1e37f) ? 0.f : __expf(s1 - mn);
      float e2 = (s2 <= -1e37f) ? 0.f : __expf(s2 - mn);
      float e3 = (s3 <= -1e37f) ? 0.f : __expf(s3 - mn);
      l = l * corr + (e0 + e1) + (e2 + e3);
      accO[0] *= corr; accO[1] *= corr; accO[2] *= corr; accO[3] *= corr;
      s4 pf = __builtin_bit_cast(s4, make_uint2(cvtpk(e0, e1), cvtpk(e2, e3)));
      s4 vf = *(const s4*)&Vt[fr][qt * 16 + g * 4];
      accO = mfma16(vf, pf, accO);
    }

    float lt = l;
    lt += __shfl_xor(lt, 16);
    lt += __shfl_xor(lt, 32);
    const float inv = 1.f / lt;

    const int q_glob = qt * 16 + fr;
    u32 lo = cvtpk(accO[0] * inv, accO[1] * inv);
    u32 hi = cvtpk(accO[2] * inv, accO[3] * inv);
    *(uint2*)(out + (size_t)(b * TSEQ + q_glob) * CDIM + h * HD + 4 * g) =
        make_uint2(lo, hi);
  }
}

// ----------------------------------------------------------------- host ----
extern "C" void kernel_launch(void* const* d_in, const int* in_sizes, int n_in,
                              void* d_out, int out_size, void* d_ws, size_t ws_size,
                              hipStream_t stream) {
  const int*   tokens  = (const int*)  d_in[0];
  const float* tok_emb = (const float*)d_in[1];
  const float* pos_emb = (const float*)d_in[2];
  const float* Wq      = (const float*)d_in[3];
  const float* Wk      = (const float*)d_in[4];
  const float* Wv      = (const float*)d_in[5];
  const float* Wproj   = (const float*)d_in[6];
  const float* bproj   = (const float*)d_in[7];
  const float* ln1_g   = (const float*)d_in[8];
  const float* ln1_b   = (const float*)d_in[9];
  const float* ln2_g   = (const float*)d_in[10];
  const float* ln2_b   = (const float*)d_in[11];
  const float* W1      = (const float*)d_in[12];
  const float* b1      = (const float*)d_in[13];
  const float* W2      = (const float*)d_in[14];
  const float* b2      = (const float*)d_in[15];
  const float* lnf_g   = (const float*)d_in[16];
  const float* lnf_b   = (const float*)d_in[17];
  const float* Wlm     = (const float*)d_in[18];
  const float* blm     = (const float*)d_in[19];
  float* out = (float*)d_out;

  char* W = (char*)d_ws;
  float* x    = (float*)(W);                   // 16384*128 f32      (8 MB)
  u16*   qkvb = (u16*)  (W + 12582912);        // 16384*384 bf16     (12 MB)
  u16*   att  = (u16*)  (W + 25165824);        // 16384*128 bf16     (4 MB)
  u16*   hbuf = (u16*)  (W + 29360128);        // 16384*512 bf16     (16 MB)
  u16*   wqkv = (u16*)  (W + 46137344);        // 6*384*128
  u16*   wpj  = (u16*)  (W + 46727168);        // 6*128*128
  u16*   w1t  = (u16*)  (W + 46923776);        // 6*512*128
  u16*   w2t  = (u16*)  (W + 47710208);        // 6*128*512
  u16*   wlmt = (u16*)  (W + 48496640);        // 3149*128

  packqkv_bf16<<<(NL * 384 * CDIM + 255) / 256, 256, 0, stream>>>(Wq, Wk, Wv, wqkv);
  transpose_cast_t<<<dim3(4, 4, NL), 256, 0, stream>>>(Wproj, wpj, CDIM, CDIM);
  transpose_cast_t<<<dim3(16, 4, NL), 256, 0, stream>>>(W1, w1t, CDIM, FFD);
  transpose_cast_t<<<dim3(4, 16, NL), 256, 0, stream>>>(W2, w2t, FFD, CDIM);
  transpose_cast_t<<<dim3((NV + 31) / 32, 4, 1), 256, 0, stream>>>(Wlm, wlmt, CDIM, NV);
  embed_kernel<<<(BT * CDIM / 4 + 255) / 256, 256, 0, stream>>>(tokens, tok_emb, pos_emb, x);

  for (int l = 0; l < NL; l++) {
    gemm_k128<0, false, false, true, 128><<<dim3(3, BT / 64), 256, 0, stream>>>(
        x, wqkv + (size_t)l * 384 * CDIM, ln1_g + l * CDIM, ln1_b + l * CDIM,
        nullptr, qkvb, BT, 384);
    attn_mfma<<<NBAT * NH * 2, 256, 0, stream>>>(qkvb, att);
    gemm_k128<2, true, false, false, 64><<<dim3(2, BT / 64), 256, 0, stream>>>(
        att, wpj + (size_t)l * CDIM * CDIM, nullptr, nullptr,
        bproj + l * CDIM, x, BT, CDIM);
    gemm_k128<0, true, true, true, 128><<<dim3(4, BT / 64), 256, 0, stream>>>(
        x, w1t + (size_t)l * FFD * CDIM, ln2_g + l * CDIM, ln2_b + l * CDIM,
        b1 + l * FFD, hbuf, BT, FFD);
    gemm_dbuf64<2, true, false><<<dim3(2, BT / 64), 256, 0, stream>>>(
        hbuf, w2t + (size_t)l * CDIM * FFD, b2 + l * CDIM, x, BT, CDIM, FFD);
  }
  gemm_k128<1, true, false, true, 128><<<dim3((NV + 127) / 128, BT / 64), 256, 0, stream>>>(
      x, wlmt, lnf_g, lnf_b, blm, out, BT, NV);
}